// Round 20
// baseline (52.392 us; speedup 1.0000x reference)
//
#include <hip/hip_runtime.h>

#define NN 128
#define CCH 16
#define BB 4
#define HID 128
#define DOUT 128

typedef float v2f __attribute__((ext_vector_type(2)));

// ---------------------------------------------------------------------------
// Single fused kernel (R19 + per-wave k-stagger; everything else identical).
// Block = (b, row p), 512 threads = 8 waves, grid 512. XCD swizzle kept.
//
// k-stagger: wave w iterates k = (j + 16*w) & 127. All waves execute the
// same inst stream but hit their s_load waitcnt boundaries at DIFFERENT k
// phases -> one wave's scalar-load wait is covered by another's VALU burst
// (de-convoying the correlated lgkmcnt stalls; R16/R17 showed inst count
// and occupancy are not the binding terms). koff is wave-uniform, so the
// weight addresses stay scalar (s_load).
// ---------------------------------------------------------------------------
__global__ __launch_bounds__(512) void fused_rey(
    const float* __restrict__ x,
    const float* __restrict__ W1, const float* __restrict__ b1,
    const float* __restrict__ W2, const float* __restrict__ b2,
    const float* __restrict__ Wc, const float* __restrict__ bc,
    float* __restrict__ y)
{
    __shared__ float s_out[CCH][NN];   // 8 KB
    __shared__ float s_diag[CCH];

    const int t    = threadIdx.x;
    const int bid0 = blockIdx.x;
    const int bid  = ((bid0 & 7) << 6) | (bid0 >> 3);   // XCD-contiguous (bijective)
    const int p    = bid & 127;
    const int b    = bid >> 7;
    const int c    = t >> 5;           // 0..15 (half-wave uniform)
    const int qg   = t & 31;
    const int q0   = qg * 4;           // q quad {q0..q0+3}

    const float* xm = x + (((size_t)(b * CCH + c)) << 14);

    // per-thread x loads (strided ones served by per-XCD L2 post-swizzle)
    const float4 vpq = *reinterpret_cast<const float4*>(&xm[p * NN + q0]);  // coalesced
    const v2f xpq01 = { vpq.x, vpq.y }, xpq23 = { vpq.z, vpq.w };
    const v2f xqp01 = { xm[q0 * NN + p],       xm[(q0 + 1) * NN + p] };
    const v2f xqp23 = { xm[(q0 + 2) * NN + p], xm[(q0 + 3) * NN + p] };
    const v2f xqq01 = { xm[q0 * (NN + 1)],       xm[(q0 + 1) * (NN + 1)] };
    const v2f xqq23 = { xm[(q0 + 2) * (NN + 1)], xm[(q0 + 3) * (NN + 1)] };
    const float xpp = xm[p * (NN + 1)];

    const float bb0 = b2[0], bb1 = b2[1];
    const v2f z2 = { 0.f, 0.f };
    v2f h0a = z2, h0b = z2, h1a = z2, h1b = z2;

    // ---- phase 1: hidden loop, wave-staggered k start ----
    const int koff = (t >> 6) << 4;    // wave id * 16 (wave-uniform)
    #pragma unroll 8
    for (int j = 0; j < HID; ++j) {
        const int k = (j + koff) & (HID - 1);
        const float4 w  = reinterpret_cast<const float4*>(W1)[k];  // s_load_dwordx4
        const float b1k = b1[k];
        const float w20 = W2[k];
        const float w21 = W2[HID + k];
        const float a = fmaf(w.x, xpp, b1k);       // q-invariant, shared by 4 q's
        const v2f av  = { a, a };
        const v2f wy  = { w.y, w.y }, wz = { w.z, w.z }, ww = { w.w, w.w };
        const v2f w20v = { w20, w20 }, w21v = { w21, w21 };

        v2f hd0 = __builtin_elementwise_fma(wy, xpq01, av);
        hd0 = __builtin_elementwise_fma(wz, xqp01, hd0);
        hd0 = __builtin_elementwise_fma(ww, xqq01, hd0);
        hd0 = __builtin_elementwise_max(hd0, z2);
        h0a = __builtin_elementwise_fma(w20v, hd0, h0a);
        h1a = __builtin_elementwise_fma(w21v, hd0, h1a);

        v2f hd1 = __builtin_elementwise_fma(wy, xpq23, av);
        hd1 = __builtin_elementwise_fma(wz, xqp23, hd1);
        hd1 = __builtin_elementwise_fma(ww, xqq23, hd1);
        hd1 = __builtin_elementwise_max(hd1, z2);
        h0b = __builtin_elementwise_fma(w20v, hd1, h0b);
        h1b = __builtin_elementwise_fma(w21v, hd1, h1b);
    }

    // off-diagonal h1 (+b2[1]) -> LDS row c (16B store); (c,p) fixed after barrier
    float4 o;
    o.x = h1a[0] + bb1; o.y = h1a[1] + bb1;
    o.z = h1b[0] + bb1; o.w = h1b[1] + bb1;
    *reinterpret_cast<float4*>(&s_out[c][q0]) = o;

    // diag partial: mask q==p, reduce across the 32 lanes of this c
    float s = ((q0 == p)     ? 0.f : h0a[0]) + ((q0 + 1 == p) ? 0.f : h0a[1])
            + ((q0 + 2 == p) ? 0.f : h0b[0]) + ((q0 + 3 == p) ? 0.f : h0b[1]);
    #pragma unroll
    for (int off = 16; off > 0; off >>= 1)
        s += __shfl_down(s, off, 32);
    if (qg == 0) s_diag[c] = s * (1.0f / (NN - 1)) + bb0;

    __syncthreads();
    if (t < CCH) s_out[t][p] = s_diag[t];
    __syncthreads();

    // ---- phase 2: y[b,d,p,:] = relu(sum_c s_out[c]*Wc[d][c] + bc[d]) ----
    const int wv   = t >> 6;           // 0..7 -> 16 d's each (wave-uniform)
    const int lane = t & 63;
    const int m0   = lane * 2;
    v2f r[CCH];
    #pragma unroll
    for (int cc = 0; cc < CCH; ++cc)
        r[cc] = *reinterpret_cast<const v2f*>(&s_out[cc][m0]);

    #pragma unroll 4
    for (int dd = 0; dd < 16; ++dd) {
        const int d = wv * 16 + dd;        // wave-uniform
        const float bcv = bc[d];           // scalar load
        v2f acc = { bcv, bcv };
        #pragma unroll
        for (int cc = 0; cc < CCH; ++cc) {
            const float wcf = Wc[d * CCH + cc];   // scalar load
            acc = __builtin_elementwise_fma((v2f){ wcf, wcf }, r[cc], acc);
        }
        acc = __builtin_elementwise_max(acc, z2);
        *reinterpret_cast<v2f*>(
            &y[(((size_t)(b * DOUT + d)) * NN + p) * NN + m0]) = acc;
    }
}

extern "C" void kernel_launch(void* const* d_in, const int* in_sizes, int n_in,
                              void* d_out, int out_size, void* d_ws, size_t ws_size,
                              hipStream_t stream) {
    const float* x  = (const float*)d_in[0];
    const float* W1 = (const float*)d_in[1];
    const float* b1 = (const float*)d_in[2];
    const float* W2 = (const float*)d_in[3];
    const float* b2 = (const float*)d_in[4];
    const float* Wc = (const float*)d_in[5];
    const float* bc = (const float*)d_in[6];
    float* y = (float*)d_out;

    fused_rey<<<dim3(BB * NN), 512, 0, stream>>>(x, W1, b1, W2, b2, Wc, bc, y);
}

// Round 21
// 32.879 us; speedup vs baseline: 1.5935x; 1.5935x over previous
//
#include <hip/hip_runtime.h>

#define NN 128
#define CCH 16
#define BB 4
#define HID 128
#define DOUT 128

typedef float v2f __attribute__((ext_vector_type(2)));

// ---------------------------------------------------------------------------
// Single fused kernel (R19 phase 1 byte-identical; phase 2 stores widened to
// float4/lane). Block = (b, row p), 512 threads = 8 waves, grid 512, XCD
// swizzle. __launch_bounds__(512) relaxed; #pragma unroll 8.
// ---------------------------------------------------------------------------
__global__ __launch_bounds__(512) void fused_rey(
    const float* __restrict__ x,
    const float* __restrict__ W1, const float* __restrict__ b1,
    const float* __restrict__ W2, const float* __restrict__ b2,
    const float* __restrict__ Wc, const float* __restrict__ bc,
    float* __restrict__ y)
{
    __shared__ float s_out[CCH][NN];   // 8 KB
    __shared__ float s_diag[CCH];

    const int t    = threadIdx.x;
    const int bid0 = blockIdx.x;
    const int bid  = ((bid0 & 7) << 6) | (bid0 >> 3);   // XCD-contiguous (bijective)
    const int p    = bid & 127;
    const int b    = bid >> 7;
    const int c    = t >> 5;           // 0..15 (half-wave uniform)
    const int qg   = t & 31;
    const int q0   = qg * 4;           // q quad {q0..q0+3}

    const float* xm = x + (((size_t)(b * CCH + c)) << 14);

    // per-thread x loads (strided ones served by per-XCD L2 post-swizzle)
    const float4 vpq = *reinterpret_cast<const float4*>(&xm[p * NN + q0]);  // coalesced
    const v2f xpq01 = { vpq.x, vpq.y }, xpq23 = { vpq.z, vpq.w };
    const v2f xqp01 = { xm[q0 * NN + p],       xm[(q0 + 1) * NN + p] };
    const v2f xqp23 = { xm[(q0 + 2) * NN + p], xm[(q0 + 3) * NN + p] };
    const v2f xqq01 = { xm[q0 * (NN + 1)],       xm[(q0 + 1) * (NN + 1)] };
    const v2f xqq23 = { xm[(q0 + 2) * (NN + 1)], xm[(q0 + 3) * (NN + 1)] };
    const float xpp = xm[p * (NN + 1)];

    const float bb0 = b2[0], bb1 = b2[1];
    const v2f z2 = { 0.f, 0.f };
    v2f h0a = z2, h0b = z2, h1a = z2, h1b = z2;

    // ---- phase 1: hidden loop (R19 verbatim) ----
    #pragma unroll 8
    for (int k = 0; k < HID; ++k) {
        const float4 w  = reinterpret_cast<const float4*>(W1)[k];  // s_load_dwordx4
        const float b1k = b1[k];
        const float w20 = W2[k];
        const float w21 = W2[HID + k];
        const float a = fmaf(w.x, xpp, b1k);       // q-invariant, shared by 4 q's
        const v2f av  = { a, a };
        const v2f wy  = { w.y, w.y }, wz = { w.z, w.z }, ww = { w.w, w.w };
        const v2f w20v = { w20, w20 }, w21v = { w21, w21 };

        v2f hd0 = __builtin_elementwise_fma(wy, xpq01, av);
        hd0 = __builtin_elementwise_fma(wz, xqp01, hd0);
        hd0 = __builtin_elementwise_fma(ww, xqq01, hd0);
        hd0 = __builtin_elementwise_max(hd0, z2);
        h0a = __builtin_elementwise_fma(w20v, hd0, h0a);
        h1a = __builtin_elementwise_fma(w21v, hd0, h1a);

        v2f hd1 = __builtin_elementwise_fma(wy, xpq23, av);
        hd1 = __builtin_elementwise_fma(wz, xqp23, hd1);
        hd1 = __builtin_elementwise_fma(ww, xqq23, hd1);
        hd1 = __builtin_elementwise_max(hd1, z2);
        h0b = __builtin_elementwise_fma(w20v, hd1, h0b);
        h1b = __builtin_elementwise_fma(w21v, hd1, h1b);
    }

    // off-diagonal h1 (+b2[1]) -> LDS row c; (c,p) fixed after barrier
    float4 o;
    o.x = h1a[0] + bb1; o.y = h1a[1] + bb1;
    o.z = h1b[0] + bb1; o.w = h1b[1] + bb1;
    *reinterpret_cast<float4*>(&s_out[c][q0]) = o;

    // diag partial: mask q==p, reduce across the 32 lanes of this c
    float s = ((q0 == p)     ? 0.f : h0a[0]) + ((q0 + 1 == p) ? 0.f : h0a[1])
            + ((q0 + 2 == p) ? 0.f : h0b[0]) + ((q0 + 3 == p) ? 0.f : h0b[1]);
    #pragma unroll
    for (int off = 16; off > 0; off >>= 1)
        s += __shfl_down(s, off, 32);
    if (qg == 0) s_diag[c] = s * (1.0f / (NN - 1)) + bb0;

    __syncthreads();
    if (t < CCH) s_out[t][p] = s_diag[t];
    __syncthreads();

    // ---- phase 2: float4/lane stores ----
    // wave wv: 16 d's; lane: m-quad m0 = (lane&31)*4, d-half dh = lane>>5.
    // Iter dd handles d = wv*16 + dd*2 + dh -> full wave covers 2 d's/iter,
    // 64 lanes x 16B = two 512B rows per store inst.
    const int wv   = t >> 6;           // 0..7 (wave-uniform)
    const int lane = t & 63;
    const int m0   = (lane & 31) * 4;
    const int dh   = lane >> 5;        // 0..1
    float4 r[CCH];
    #pragma unroll
    for (int cc = 0; cc < CCH; ++cc)
        r[cc] = *reinterpret_cast<const float4*>(&s_out[cc][m0]);   // conflict-free b128

    #pragma unroll 2
    for (int dd = 0; dd < 8; ++dd) {
        const int d = wv * 16 + dd * 2 + dh;
        const float bcv = bc[d];
        float4 acc = { bcv, bcv, bcv, bcv };
        #pragma unroll
        for (int cc = 0; cc < CCH; ++cc) {
            const float wcf = Wc[d * CCH + cc];
            acc.x = fmaf(wcf, r[cc].x, acc.x);
            acc.y = fmaf(wcf, r[cc].y, acc.y);
            acc.z = fmaf(wcf, r[cc].z, acc.z);
            acc.w = fmaf(wcf, r[cc].w, acc.w);
        }
        acc.x = fmaxf(acc.x, 0.f);
        acc.y = fmaxf(acc.y, 0.f);
        acc.z = fmaxf(acc.z, 0.f);
        acc.w = fmaxf(acc.w, 0.f);
        *reinterpret_cast<float4*>(
            &y[(((size_t)(b * DOUT + d)) * NN + p) * NN + m0]) = acc;
    }
}

extern "C" void kernel_launch(void* const* d_in, const int* in_sizes, int n_in,
                              void* d_out, int out_size, void* d_ws, size_t ws_size,
                              hipStream_t stream) {
    const float* x  = (const float*)d_in[0];
    const float* W1 = (const float*)d_in[1];
    const float* b1 = (const float*)d_in[2];
    const float* W2 = (const float*)d_in[3];
    const float* b2 = (const float*)d_in[4];
    const float* Wc = (const float*)d_in[5];
    const float* bc = (const float*)d_in[6];
    float* y = (float*)d_out;

    fused_rey<<<dim3(BB * NN), 512, 0, stream>>>(x, W1, b1, W2, b2, Wc, bc, y);
}